// Round 1
// baseline (121.053 us; speedup 1.0000x reference)
//
#include <hip/hip_runtime.h>
#include <hip/hip_bf16.h>
#include <stdint.h>

#define B_ 2
#define L_ 2048
#define C_ 16
#define D_ 64
#define H_ 64
#define QBLK 128
#define KVBLK 64
#define NTHREADS 512

typedef __attribute__((ext_vector_type(8))) short bf16x8;
typedef __attribute__((ext_vector_type(4))) float f32x4;
typedef __attribute__((ext_vector_type(4))) unsigned short u16x4;

__device__ inline unsigned short f2bf(float f) {
  union { float f; unsigned int u; } v; v.f = f;
  unsigned int u = v.u;
  // round-to-nearest-even bf16
  unsigned int r = (u + 0x7FFFu + ((u >> 16) & 1u)) >> 16;
  return (unsigned short)r;
}

__device__ inline float fast_exp2(float x) {
#if __has_builtin(__builtin_amdgcn_exp2f)
  return __builtin_amdgcn_exp2f(x);
#else
  return exp2f(x);
#endif
}

// Flash-attention forward. One block = one (b,c) head x 128 query rows.
// 8 waves, each wave owns 16 q-rows. KV tiles of 64, online softmax.
__global__ __launch_bounds__(NTHREADS, 2) void attn_fwd_kernel(
    const float* __restrict__ Qg, const float* __restrict__ Kg,
    const float* __restrict__ Vg, float* __restrict__ Og) {
  // swizzled LDS tiles: elem index = row*64 + (col ^ ((row&7)<<3))
  __shared__ unsigned short Ks[KVBLK * 64];   // [kv][d]   8 KB
  __shared__ unsigned short Vt[64 * KVBLK];   // [h][kv]   8 KB (transposed V)
  __shared__ unsigned short Ps[QBLK * 64];    // [q][kv]  16 KB

  const int tid  = threadIdx.x;
  const int lane = tid & 63;
  const int w    = tid >> 6;       // wave id 0..7
  const int lo   = lane & 15;
  const int hi   = lane >> 4;      // 0..3

  // XCD-aware swizzle: 512 blocks, 8 XCDs -> 64 contiguous per XCD
  const int bid   = blockIdx.x;
  const int swz   = (bid & 7) * 64 + (bid >> 3);
  const int head  = swz >> 4;      // 0..31
  const int qtile = swz & 15;      // 0..15
  const int b     = head >> 4;     // /C_
  const int c     = head & 15;
  const int q0    = qtile * QBLK;

  // ---- preload this wave's Q fragments into registers (2 k-steps of 32 d) ----
  const int qr = q0 + w * 16 + lo;
  const float* qrow = Qg + ((size_t)(b * L_ + qr) * C_ + c) * D_;
  bf16x8 qf[2];
#pragma unroll
  for (int ks = 0; ks < 2; ++ks) {
    float4 a0 = *(const float4*)(qrow + ks * 32 + hi * 8);
    float4 a1 = *(const float4*)(qrow + ks * 32 + hi * 8 + 4);
    bf16x8 q8;
    q8[0] = (short)f2bf(a0.x); q8[1] = (short)f2bf(a0.y);
    q8[2] = (short)f2bf(a0.z); q8[3] = (short)f2bf(a0.w);
    q8[4] = (short)f2bf(a1.x); q8[5] = (short)f2bf(a1.y);
    q8[6] = (short)f2bf(a1.z); q8[7] = (short)f2bf(a1.w);
    qf[ks] = q8;
  }

  f32x4 o[4];
#pragma unroll
  for (int i = 0; i < 4; ++i) o[i] = (f32x4){0.f, 0.f, 0.f, 0.f};
  float m_i[4] = {-1e30f, -1e30f, -1e30f, -1e30f};
  float l_i[4] = {0.f, 0.f, 0.f, 0.f};

  const float sc2 = 0.125f * 1.44269504088896340736f;  // scale * log2(e)

  for (int t = 0; t < L_ / KVBLK; ++t) {
    const int m0 = t * KVBLK;
    __syncthreads();  // previous PV reads done before overwriting Ks/Vt

    // ---- stage K tile [64 kv][64 d] fp32->bf16, swizzled ----
#pragma unroll
    for (int it = 0; it < 2; ++it) {
      int flat = it * NTHREADS + tid;
      int row  = flat >> 4;          // 0..63
      int c4   = (flat & 15) * 4;    // 0..60
      const float4 kd = *(const float4*)(Kg + ((size_t)(b * L_ + m0 + row) * C_ + c) * D_ + c4);
      u16x4 pk;
      pk.x = f2bf(kd.x); pk.y = f2bf(kd.y); pk.z = f2bf(kd.z); pk.w = f2bf(kd.w);
      *(u16x4*)&Ks[row * 64 + (c4 ^ ((row & 7) << 3))] = pk;
    }
    // ---- stage V tile transposed: Vt[h][kv], coalesced loads ----
#pragma unroll
    for (int it = 0; it < 2; ++it) {
      int flat = it * NTHREADS + tid;
      int h    = flat & 63;
      int kvg  = (flat >> 6) * 4;    // 0,4,...,60
      const float* vp = Vg + ((size_t)(b * L_ + m0 + kvg) * C_ + c) * H_ + h;
      u16x4 pv;
      pv.x = f2bf(vp[0]);
      pv.y = f2bf(vp[(size_t)C_ * H_]);
      pv.z = f2bf(vp[2 * (size_t)C_ * H_]);
      pv.w = f2bf(vp[3 * (size_t)C_ * H_]);
      *(u16x4*)&Vt[h * 64 + (kvg ^ ((h & 7) << 3))] = pv;
    }
    __syncthreads();

    // ---- S = Q.K^T for this wave's 16 q-rows x 64 kv ----
    f32x4 s[4];
#pragma unroll
    for (int i = 0; i < 4; ++i) s[i] = (f32x4){0.f, 0.f, 0.f, 0.f};
#pragma unroll
    for (int ct = 0; ct < 4; ++ct) {
      int krow = ct * 16 + lo;
      const bf16x8 b0 = *(const bf16x8*)&Ks[krow * 64 + ((hi * 8) ^ ((krow & 7) << 3))];
      const bf16x8 b1 = *(const bf16x8*)&Ks[krow * 64 + ((32 + hi * 8) ^ ((krow & 7) << 3))];
      s[ct] = __builtin_amdgcn_mfma_f32_16x16x32_bf16(qf[0], b0, s[ct], 0, 0, 0);
      s[ct] = __builtin_amdgcn_mfma_f32_16x16x32_bf16(qf[1], b1, s[ct], 0, 0, 0);
    }

    // ---- online softmax; lane holds rows (w*16 + hi*4 + r), cols (ct*16+lo) ----
    float p[4][4];
#pragma unroll
    for (int r = 0; r < 4; ++r) {
      float rm = fmaxf(fmaxf(s[0][r], s[1][r]), fmaxf(s[2][r], s[3][r]));
      rm = fmaxf(rm, __shfl_xor(rm, 1));
      rm = fmaxf(rm, __shfl_xor(rm, 2));
      rm = fmaxf(rm, __shfl_xor(rm, 4));
      rm = fmaxf(rm, __shfl_xor(rm, 8));
      float m_new  = fmaxf(m_i[r], rm * sc2);
      float sc_old = fast_exp2(m_i[r] - m_new);
      float rs = 0.f;
#pragma unroll
      for (int ct = 0; ct < 4; ++ct) {
        float pv = fast_exp2(s[ct][r] * sc2 - m_new);
        p[ct][r] = pv;
        rs += pv;
      }
      rs += __shfl_xor(rs, 1);
      rs += __shfl_xor(rs, 2);
      rs += __shfl_xor(rs, 4);
      rs += __shfl_xor(rs, 8);
      l_i[r] = l_i[r] * sc_old + rs;
      m_i[r] = m_new;
      o[0][r] *= sc_old; o[1][r] *= sc_old; o[2][r] *= sc_old; o[3][r] *= sc_old;
    }

    // ---- write P (bf16, swizzled [q][kv]) ----
#pragma unroll
    for (int ct = 0; ct < 4; ++ct) {
#pragma unroll
      for (int r = 0; r < 4; ++r) {
        int qlr = w * 16 + hi * 4 + r;
        int col = ct * 16 + lo;
        Ps[qlr * 64 + (col ^ ((qlr & 7) << 3))] = f2bf(p[ct][r]);
      }
    }
    __syncthreads();  // Ps visible (cross-lane) before PV reads

    // ---- O += P.V ----
    const int qlr = w * 16 + lo;
    const bf16x8 pf0 = *(const bf16x8*)&Ps[qlr * 64 + ((hi * 8) ^ ((qlr & 7) << 3))];
    const bf16x8 pf1 = *(const bf16x8*)&Ps[qlr * 64 + ((32 + hi * 8) ^ ((qlr & 7) << 3))];
#pragma unroll
    for (int hct = 0; hct < 4; ++hct) {
      int vrow = hct * 16 + lo;
      const bf16x8 v0 = *(const bf16x8*)&Vt[vrow * 64 + ((hi * 8) ^ ((vrow & 7) << 3))];
      const bf16x8 v1 = *(const bf16x8*)&Vt[vrow * 64 + ((32 + hi * 8) ^ ((vrow & 7) << 3))];
      o[hct] = __builtin_amdgcn_mfma_f32_16x16x32_bf16(pf0, v0, o[hct], 0, 0, 0);
      o[hct] = __builtin_amdgcn_mfma_f32_16x16x32_bf16(pf1, v1, o[hct], 0, 0, 0);
    }
  }

  // ---- epilogue: normalize and store fp32 ----
#pragma unroll
  for (int r = 0; r < 4; ++r) {
    float inv = 1.0f / l_i[r];
    int qrow = q0 + w * 16 + hi * 4 + r;
    float* orow = Og + ((size_t)(b * L_ + qrow) * C_ + c) * H_;
#pragma unroll
    for (int hct = 0; hct < 4; ++hct) {
      orow[hct * 16 + lo] = o[hct][r] * inv;
    }
  }
}

extern "C" void kernel_launch(void* const* d_in, const int* in_sizes, int n_in,
                              void* d_out, int out_size, void* d_ws, size_t ws_size,
                              hipStream_t stream) {
  const float* Qg = (const float*)d_in[0];
  const float* Kg = (const float*)d_in[1];
  const float* Vg = (const float*)d_in[2];
  float* Og = (float*)d_out;
  const int nheads = B_ * C_;                 // 32
  const int nqtiles = L_ / QBLK;              // 16
  dim3 grid(nheads * nqtiles);                // 512 blocks
  dim3 block(NTHREADS);
  attn_fwd_kernel<<<grid, block, 0, stream>>>(Qg, Kg, Vg, Og);
}

// Round 2
// 91.685 us; speedup vs baseline: 1.3203x; 1.3203x over previous
//
#include <hip/hip_runtime.h>
#include <hip/hip_bf16.h>
#include <stdint.h>

#define B_ 2
#define L_ 2048
#define C_ 16
#define D_ 64
#define H_ 64
#define QBLK 128
#define KVBLK 64
#define NTILES 32            // L_/KVBLK
#define NTHREADS 512
#define NHEADS 32            // B_*C_
#define TILE_ELEMS 4096      // KVBLK*64 bf16 elements (8KB)
#define TENSOR_ELEMS (NHEADS * NTILES * TILE_ELEMS)  // 4,194,304

typedef __attribute__((ext_vector_type(8))) short bf16x8;
typedef __attribute__((ext_vector_type(4))) float f32x4;
typedef __attribute__((ext_vector_type(8))) unsigned short u16x8;

__device__ inline unsigned short f2bf(float f) {
  union { float f; unsigned int u; } v; v.f = f;
  unsigned int u = v.u;
  unsigned int r = (u + 0x7FFFu + ((u >> 16) & 1u)) >> 16;  // RNE
  return (unsigned short)r;
}

__device__ inline float fast_exp2(float x) {
#if __has_builtin(__builtin_amdgcn_exp2f)
  return __builtin_amdgcn_exp2f(x);
#else
  return exp2f(x);
#endif
}

__device__ inline void gload_lds16(const unsigned short* g, unsigned short* l) {
  __builtin_amdgcn_global_load_lds(
      (const __attribute__((address_space(1))) unsigned int*)g,
      (__attribute__((address_space(3))) unsigned int*)l, 16, 0, 0);
}

// ---------------- pre-pass: fp32 -> bf16, pre-transposed + pre-swizzled ----
// Kb tile layout (linear in global == linear in LDS after plain copy):
//   Kb[head][t][row][ (grp ^ (row&7))*8 + j ] = K[b][t*64+row][c][grp*8+j]
// Vb tile layout:
//   Vb[head][t][h]  [ (grp ^ (h&7))*8 + j ]   = V[b][t*64+grp*8+j][c][h]
__global__ __launch_bounds__(256) void prepack_kernel(
    const float* __restrict__ Kg, const float* __restrict__ Vg,
    unsigned short* __restrict__ Kb, unsigned short* __restrict__ Vb) {
  int idx = blockIdx.x * 256 + threadIdx.x;     // 0 .. 2*524288-1
  if (idx < 524288) {
    int i = idx;
    int grp = i & 7, row = (i >> 3) & 63, t = (i >> 9) & 31, head = i >> 14;
    int b = head >> 4, c = head & 15;
    const float* src = Kg + ((size_t)(b * L_ + t * 64 + row) * C_ + c) * D_ + grp * 8;
    float4 a0 = ((const float4*)src)[0];
    float4 a1 = ((const float4*)src)[1];
    u16x8 pk;
    pk[0] = f2bf(a0.x); pk[1] = f2bf(a0.y); pk[2] = f2bf(a0.z); pk[3] = f2bf(a0.w);
    pk[4] = f2bf(a1.x); pk[5] = f2bf(a1.y); pk[6] = f2bf(a1.z); pk[7] = f2bf(a1.w);
    size_t dst = ((size_t)(head * 32 + t) * 64 + row) * 64 + ((grp ^ (row & 7)) * 8);
    *(u16x8*)&Kb[dst] = pk;
  } else {
    int i = idx - 524288;
    int h = i & 63, grp = (i >> 6) & 7, t = (i >> 9) & 31, head = i >> 14;
    int b = head >> 4, c = head & 15;
    const float* src = Vg + ((size_t)(b * L_ + t * 64 + grp * 8) * C_ + c) * H_ + h;
    u16x8 pv;
#pragma unroll
    for (int j = 0; j < 8; ++j) pv[j] = f2bf(src[(size_t)j * C_ * H_]);
    size_t dst = ((size_t)(head * 32 + t) * 64 + h) * 64 + ((grp ^ (h & 7)) * 8);
    *(u16x8*)&Vb[dst] = pv;
  }
}

// ---------------- flash-attention forward ---------------------------------
__global__ __launch_bounds__(NTHREADS, 2) void attn_fwd_kernel(
    const float* __restrict__ Qg,
    const unsigned short* __restrict__ Kb,
    const unsigned short* __restrict__ Vb,
    float* __restrict__ Og) {
  __shared__ unsigned short Ks2[2][TILE_ELEMS];  // 16 KB (double-buffered K)
  __shared__ unsigned short Vt2[2][TILE_ELEMS];  // 16 KB (double-buffered V^T)
  __shared__ unsigned short Ps[QBLK * 64];       // 16 KB

  const int tid  = threadIdx.x;
  const int lane = tid & 63;
  const int w    = tid >> 6;
  const int lo   = lane & 15;
  const int hi   = lane >> 4;

  const int bid   = blockIdx.x;
  const int swz   = (bid & 7) * 64 + (bid >> 3);   // XCD-contiguous
  const int head  = swz >> 4;
  const int qtile = swz & 15;
  const int b     = head >> 4;
  const int c     = head & 15;
  const int q0    = qtile * QBLK;

  const unsigned short* KbH = Kb + (size_t)head * NTILES * TILE_ELEMS;
  const unsigned short* VbH = Vb + (size_t)head * NTILES * TILE_ELEMS;

  // Q fragments (once): row = lo, k = ks*32 + hi*8 + j
  const int qr = q0 + w * 16 + lo;
  const float* qrow = Qg + ((size_t)(b * L_ + qr) * C_ + c) * D_;
  bf16x8 qf[2];
#pragma unroll
  for (int ks = 0; ks < 2; ++ks) {
    float4 a0 = *(const float4*)(qrow + ks * 32 + hi * 8);
    float4 a1 = *(const float4*)(qrow + ks * 32 + hi * 8 + 4);
    bf16x8 q8;
    q8[0] = (short)f2bf(a0.x); q8[1] = (short)f2bf(a0.y);
    q8[2] = (short)f2bf(a0.z); q8[3] = (short)f2bf(a0.w);
    q8[4] = (short)f2bf(a1.x); q8[5] = (short)f2bf(a1.y);
    q8[6] = (short)f2bf(a1.z); q8[7] = (short)f2bf(a1.w);
    qf[ks] = q8;
  }

  // ones B-fragment: B[k][col] = (col==0) ? 1 : 0  -> rowsum accumulator
  bf16x8 bones = (bf16x8)(short)0;
  if (lo == 0) {
#pragma unroll
    for (int j = 0; j < 8; ++j) bones[j] = (short)0x3F80;
  }

  f32x4 o[4];
#pragma unroll
  for (int i = 0; i < 4; ++i) o[i] = (f32x4){0.f, 0.f, 0.f, 0.f};
  f32x4 o_l = (f32x4){0.f, 0.f, 0.f, 0.f};
  float m_i[4] = {-1e30f, -1e30f, -1e30f, -1e30f};

  const float sc2 = 0.125f * 1.44269504088896340736f;  // scale * log2(e)

  // prologue: stage tile 0 into buffer 0
  gload_lds16(KbH + (size_t)tid * 8, &Ks2[0][tid * 8]);
  gload_lds16(VbH + (size_t)tid * 8, &Vt2[0][tid * 8]);
  __syncthreads();  // implicit vmcnt(0) drain before s_barrier

  int cur = 0;
  for (int t = 0; t < NTILES; ++t) {
    const unsigned short* KsB = Ks2[cur];
    const unsigned short* VtB = Vt2[cur];

    // ---- S = Q.K^T ----
    f32x4 s[4];
#pragma unroll
    for (int i = 0; i < 4; ++i) s[i] = (f32x4){0.f, 0.f, 0.f, 0.f};
#pragma unroll
    for (int ct = 0; ct < 4; ++ct) {
      int krow = ct * 16 + lo;
      const bf16x8 b0 = *(const bf16x8*)&KsB[krow * 64 + ((hi * 8) ^ ((krow & 7) << 3))];
      const bf16x8 b1 = *(const bf16x8*)&KsB[krow * 64 + ((32 + hi * 8) ^ ((krow & 7) << 3))];
      s[ct] = __builtin_amdgcn_mfma_f32_16x16x32_bf16(qf[0], b0, s[ct], 0, 0, 0);
      s[ct] = __builtin_amdgcn_mfma_f32_16x16x32_bf16(qf[1], b1, s[ct], 0, 0, 0);
    }

    // ---- online softmax with defer-max ----
    float rms[4];
#pragma unroll
    for (int r = 0; r < 4; ++r) {
      float rm = fmaxf(fmaxf(s[0][r], s[1][r]), fmaxf(s[2][r], s[3][r]));
      rm = fmaxf(rm, __shfl_xor(rm, 1));
      rm = fmaxf(rm, __shfl_xor(rm, 2));
      rm = fmaxf(rm, __shfl_xor(rm, 4));
      rm = fmaxf(rm, __shfl_xor(rm, 8));
      rms[r] = rm * sc2;
    }
    bool need = (rms[0] > m_i[0] + 8.f) || (rms[1] > m_i[1] + 8.f) ||
                (rms[2] > m_i[2] + 8.f) || (rms[3] > m_i[3] + 8.f);
    if (__any(need)) {
#pragma unroll
      for (int r = 0; r < 4; ++r) {
        float mn = fmaxf(m_i[r], rms[r]);
        float so = fast_exp2(m_i[r] - mn);
        m_i[r] = mn;
        o[0][r] *= so; o[1][r] *= so; o[2][r] *= so; o[3][r] *= so;
        o_l[r] *= so;
      }
    }

    // ---- P = exp2(S*sc2 - m), write bf16 swizzled ----
#pragma unroll
    for (int ct = 0; ct < 4; ++ct) {
#pragma unroll
      for (int r = 0; r < 4; ++r) {
        float pv = fast_exp2(__builtin_fmaf(s[ct][r], sc2, -m_i[r]));
        int qlr = w * 16 + hi * 4 + r;
        int col = ct * 16 + lo;
        Ps[qlr * 64 + (col ^ ((qlr & 7) << 3))] = f2bf(pv);
      }
    }
    __syncthreads();  // B: Ps visible

    // ---- stage next tile into the other buffer (flies under PV) ----
    if (t + 1 < NTILES) {
      const size_t toff = (size_t)(t + 1) * TILE_ELEMS + tid * 8;
      gload_lds16(KbH + toff, &Ks2[cur ^ 1][tid * 8]);
      gload_lds16(VbH + toff, &Vt2[cur ^ 1][tid * 8]);
    }

    // ---- O += P.V  (plus rowsum via ones-column) ----
    const int qlr = w * 16 + lo;
    const bf16x8 pf0 = *(const bf16x8*)&Ps[qlr * 64 + ((hi * 8) ^ ((qlr & 7) << 3))];
    const bf16x8 pf1 = *(const bf16x8*)&Ps[qlr * 64 + ((32 + hi * 8) ^ ((qlr & 7) << 3))];
#pragma unroll
    for (int hct = 0; hct < 4; ++hct) {
      int vrow = hct * 16 + lo;
      const bf16x8 v0 = *(const bf16x8*)&VtB[vrow * 64 + ((hi * 8) ^ ((vrow & 7) << 3))];
      const bf16x8 v1 = *(const bf16x8*)&VtB[vrow * 64 + ((32 + hi * 8) ^ ((vrow & 7) << 3))];
      o[hct] = __builtin_amdgcn_mfma_f32_16x16x32_bf16(pf0, v0, o[hct], 0, 0, 0);
      o[hct] = __builtin_amdgcn_mfma_f32_16x16x32_bf16(pf1, v1, o[hct], 0, 0, 0);
    }
    o_l = __builtin_amdgcn_mfma_f32_16x16x32_bf16(pf0, bones, o_l, 0, 0, 0);
    o_l = __builtin_amdgcn_mfma_f32_16x16x32_bf16(pf1, bones, o_l, 0, 0, 0);

    __syncthreads();  // A: next tile staged (implicit vmcnt drain); PV reads done
    cur ^= 1;
  }

  // ---- epilogue ----
#pragma unroll
  for (int r = 0; r < 4; ++r) {
    float l_r = __shfl(o_l[r], lane & 48);  // broadcast from lo==0 lane of this hi-group
    float inv = 1.0f / l_r;
    int qrow = q0 + w * 16 + hi * 4 + r;
    float* orow = Og + ((size_t)(b * L_ + qrow) * C_ + c) * H_;
#pragma unroll
    for (int hct = 0; hct < 4; ++hct) {
      orow[hct * 16 + lo] = o[hct][r] * inv;
    }
  }
}

extern "C" void kernel_launch(void* const* d_in, const int* in_sizes, int n_in,
                              void* d_out, int out_size, void* d_ws, size_t ws_size,
                              hipStream_t stream) {
  const float* Qg = (const float*)d_in[0];
  const float* Kg = (const float*)d_in[1];
  const float* Vg = (const float*)d_in[2];
  float* Og = (float*)d_out;

  unsigned short* Kb = (unsigned short*)d_ws;
  unsigned short* Vb = Kb + (size_t)TENSOR_ELEMS;

  // pre-pass: 2*524288 chunks, 256 threads each
  prepack_kernel<<<4096, 256, 0, stream>>>(Kg, Vg, Kb, Vb);

  dim3 grid(NHEADS * (L_ / QBLK));   // 512 blocks
  dim3 block(NTHREADS);
  attn_fwd_kernel<<<grid, block, 0, stream>>>(Qg, Kb, Vb, Og);
}

// Round 3
// 65.519 us; speedup vs baseline: 1.8476x; 1.3994x over previous
//
#include <hip/hip_runtime.h>
#include <hip/hip_bf16.h>
#include <stdint.h>

#define B_ 2
#define L_ 2048
#define C_ 16
#define D_ 64
#define H_ 64
#define QBLK 128
#define KVBLK 64
#define NTILES 32            // L_/KVBLK
#define NTHREADS 256         // 4 waves, each owns 32 q-rows
#define NHEADS 32            // B_*C_
#define TILE_ELEMS 4096      // KVBLK*64 bf16 elements (8KB)
#define TENSOR_ELEMS (NHEADS * NTILES * TILE_ELEMS)  // 4,194,304

typedef __attribute__((ext_vector_type(8))) short bf16x8;
typedef __attribute__((ext_vector_type(16))) float f32x16;
typedef __attribute__((ext_vector_type(8))) unsigned short u16x8;

__device__ inline unsigned short f2bf(float f) {
  union { float f; unsigned int u; } v; v.f = f;
  unsigned int u = v.u;
  unsigned int r = (u + 0x7FFFu + ((u >> 16) & 1u)) >> 16;  // RNE
  return (unsigned short)r;
}

__device__ inline float fast_exp2(float x) {
#if __has_builtin(__builtin_amdgcn_exp2f)
  return __builtin_amdgcn_exp2f(x);
#else
  return exp2f(x);
#endif
}

__device__ inline void gload_lds16(const unsigned short* g, unsigned short* l) {
  __builtin_amdgcn_global_load_lds(
      (const __attribute__((address_space(1))) unsigned int*)g,
      (__attribute__((address_space(3))) unsigned int*)l, 16, 0, 0);
}

__device__ inline unsigned cvt_pk_bf16(float lo, float hi) {
  unsigned r;
  asm("v_cvt_pk_bf16_f32 %0, %1, %2" : "=v"(r) : "v"(lo), "v"(hi));
  return r;
}

// x' = {lanes<32: old x, lanes>=32: partner's old y}
// y' = {lanes<32: partner's old x, lanes>=32: old y}   (partner = lane ^ 32)
__device__ inline void pl32swap(unsigned &x, unsigned &y) {
#if __has_builtin(__builtin_amdgcn_permlane32_swap)
  auto r = __builtin_amdgcn_permlane32_swap(x, y, false, false);
  x = r[0]; y = r[1];
#else
  asm("v_permlane32_swap_b32 %0, %1" : "+v"(x), "+&v"(y));
#endif
}

__device__ inline float xmax32(float v) {
  unsigned x = __float_as_uint(v), y = x;
  pl32swap(x, y);
  return fmaxf(__uint_as_float(x), __uint_as_float(y));
}

__device__ inline float xsum32(float v) {
  unsigned x = __float_as_uint(v), y = x;
  pl32swap(x, y);
  return __uint_as_float(x) + __uint_as_float(y);
}

// ---------------- pre-pass: fp32 -> bf16, pre-transposed + pre-swizzled ----
// Kb tile: Kb[head][t][row][ (grp ^ (row&7))*8 + j ] = K[b][t*64+row][c][grp*8+j]
// Vb tile: Vb[head][t][h]  [ (grp ^ (h&7))*8 + j ]   = V[b][t*64+grp*8+j][c][h]
__global__ __launch_bounds__(256) void prepack_kernel(
    const float* __restrict__ Kg, const float* __restrict__ Vg,
    unsigned short* __restrict__ Kb, unsigned short* __restrict__ Vb) {
  int idx = blockIdx.x * 256 + threadIdx.x;     // 0 .. 2*524288-1
  if (idx < 524288) {
    int i = idx;
    int grp = i & 7, row = (i >> 3) & 63, t = (i >> 9) & 31, head = i >> 14;
    int b = head >> 4, c = head & 15;
    const float* src = Kg + ((size_t)(b * L_ + t * 64 + row) * C_ + c) * D_ + grp * 8;
    float4 a0 = ((const float4*)src)[0];
    float4 a1 = ((const float4*)src)[1];
    u16x8 pk;
    pk[0] = f2bf(a0.x); pk[1] = f2bf(a0.y); pk[2] = f2bf(a0.z); pk[3] = f2bf(a0.w);
    pk[4] = f2bf(a1.x); pk[5] = f2bf(a1.y); pk[6] = f2bf(a1.z); pk[7] = f2bf(a1.w);
    size_t dst = ((size_t)(head * 32 + t) * 64 + row) * 64 + ((grp ^ (row & 7)) * 8);
    *(u16x8*)&Kb[dst] = pk;
  } else {
    int i = idx - 524288;
    int h = i & 63, grp = (i >> 6) & 7, t = (i >> 9) & 31, head = i >> 14;
    int b = head >> 4, c = head & 15;
    const float* src = Vg + ((size_t)(b * L_ + t * 64 + grp * 8) * C_ + c) * H_ + h;
    u16x8 pv;
#pragma unroll
    for (int j = 0; j < 8; ++j) pv[j] = f2bf(src[(size_t)j * C_ * H_]);
    size_t dst = ((size_t)(head * 32 + t) * 64 + h) * 64 + ((grp ^ (h & 7)) * 8);
    *(u16x8*)&Vb[dst] = pv;
  }
}

// ---------------- flash-attention forward, 32x32 MFMA, swapped QK^T --------
__global__ __launch_bounds__(NTHREADS, 2) void attn_fwd_kernel(
    const float* __restrict__ Qg,
    const unsigned short* __restrict__ Kb,
    const unsigned short* __restrict__ Vb,
    float* __restrict__ Og) {
  __shared__ unsigned short Ks2[2][TILE_ELEMS];  // 16 KB
  __shared__ unsigned short Vt2[2][TILE_ELEMS];  // 16 KB

  const int tid  = threadIdx.x;
  const int lane = tid & 63;
  const int w    = tid >> 6;      // wave 0..3, owns q-rows w*32..+31
  const int ql   = lane & 31;     // this lane's q-row within wave
  const int u    = lane >> 5;     // k-chunk selector

  const int bid   = blockIdx.x;
  const int swz   = (bid & 7) * 64 + (bid >> 3);   // XCD-contiguous
  const int head  = swz >> 4;
  const int qtile = swz & 15;
  const int b     = head >> 4;
  const int c     = head & 15;
  const int q0    = qtile * QBLK;

  const unsigned short* KbH = Kb + (size_t)head * NTILES * TILE_ELEMS;
  const unsigned short* VbH = Vb + (size_t)head * NTILES * TILE_ELEMS;

  // Q as B-operand: col = ql (q-row), k = ks*16 + u*8 + j
  const int qr = q0 + w * 32 + ql;
  const float* qrow = Qg + ((size_t)(b * L_ + qr) * C_ + c) * D_;
  bf16x8 qf[4];
#pragma unroll
  for (int ks = 0; ks < 4; ++ks) {
    float4 a0 = *(const float4*)(qrow + ks * 16 + u * 8);
    float4 a1 = *(const float4*)(qrow + ks * 16 + u * 8 + 4);
    bf16x8 q8;
    q8[0] = (short)f2bf(a0.x); q8[1] = (short)f2bf(a0.y);
    q8[2] = (short)f2bf(a0.z); q8[3] = (short)f2bf(a0.w);
    q8[4] = (short)f2bf(a1.x); q8[5] = (short)f2bf(a1.y);
    q8[6] = (short)f2bf(a1.z); q8[7] = (short)f2bf(a1.w);
    qf[ks] = q8;
  }

  f32x16 o0, o1;   // O^T accumulators: h-blocks 0-31, 32-63
#pragma unroll
  for (int i = 0; i < 16; ++i) { o0[i] = 0.f; o1[i] = 0.f; }
  float m_i = -1e30f, l_i = 0.f;
  const float sc2 = 0.125f * 1.44269504088896340736f;  // scale * log2(e)

  // prologue: stage tile 0 into buffer 0 (2 chunks each of K and V per thread)
  gload_lds16(KbH + tid * 8, &Ks2[0][tid * 8]);
  gload_lds16(KbH + 2048 + tid * 8, &Ks2[0][2048 + tid * 8]);
  gload_lds16(VbH + tid * 8, &Vt2[0][tid * 8]);
  gload_lds16(VbH + 2048 + tid * 8, &Vt2[0][2048 + tid * 8]);
  __syncthreads();

  int cur = 0;
  for (int t = 0; t < NTILES; ++t) {
    const unsigned short* KsB = Ks2[cur];
    const unsigned short* VtB = Vt2[cur];

    // ---- S^T = K . Q^T : s0 = kv rows 0-31, s1 = kv rows 32-63 ----
    f32x16 s0, s1;
#pragma unroll
    for (int i = 0; i < 16; ++i) { s0[i] = 0.f; s1[i] = 0.f; }
#pragma unroll
    for (int ks = 0; ks < 4; ++ks) {
      const int col8 = 2 * ks + u;
      const int sw = (col8 ^ (ql & 7)) * 8;
      const bf16x8 ka0 = *(const bf16x8*)&KsB[ql * 64 + sw];
      const bf16x8 ka1 = *(const bf16x8*)&KsB[(32 + ql) * 64 + sw];
      s0 = __builtin_amdgcn_mfma_f32_32x32x16_bf16(ka0, qf[ks], s0, 0, 0, 0);
      s1 = __builtin_amdgcn_mfma_f32_32x32x16_bf16(ka1, qf[ks], s1, 0, 0, 0);
    }

    // ---- online softmax (lane owns one q-row; kv split with lane^32) ----
    float rm = s0[0];
#pragma unroll
    for (int i = 1; i < 16; ++i) rm = fmaxf(rm, s0[i]);
#pragma unroll
    for (int i = 0; i < 16; ++i) rm = fmaxf(rm, s1[i]);
    rm = xmax32(rm);
    const float rmx = rm * sc2;
    if (__any(rmx > m_i + 8.f)) {   // defer-max (T13)
      float mn = fmaxf(m_i, rmx);
      float so = fast_exp2(m_i - mn);
      m_i = mn;
#pragma unroll
      for (int i = 0; i < 16; ++i) { o0[i] *= so; o1[i] *= so; }
      l_i *= so;
    }

    // ---- P = exp2(S*sc2 - m); in-register redistribution to PV B-frags ----
    // word-group c = sb*4+g (sb = kv 32-half, g = reg-quad); PV frag m needs
    // group c=2m (lower lanes) / c=2m+1 (upper lanes) from BOTH halves:
    // one permlane32_swap per word pair places everything. pf[m] = {x0,x1,y0,y1}.
    float rs = 0.f;
    bf16x8 pf[4];
#pragma unroll
    for (int tq = 0; tq < 4; ++tq) {
      const int be = ((2 * tq) & 3) * 4;       // even-group reg base
      const int bo = ((2 * tq + 1) & 3) * 4;   // odd-group reg base
      float p0[4], p1[4];
#pragma unroll
      for (int r = 0; r < 4; ++r) {
        float se = (tq < 2) ? s0[be + r] : s1[be + r];
        float so_ = (tq < 2) ? s0[bo + r] : s1[bo + r];
        p0[r] = fast_exp2(__builtin_fmaf(se, sc2, -m_i));
        p1[r] = fast_exp2(__builtin_fmaf(so_, sc2, -m_i));
        rs += p0[r] + p1[r];
      }
      unsigned x0 = cvt_pk_bf16(p0[0], p0[1]);
      unsigned x1 = cvt_pk_bf16(p0[2], p0[3]);
      unsigned y0 = cvt_pk_bf16(p1[0], p1[1]);
      unsigned y1 = cvt_pk_bf16(p1[2], p1[3]);
      pl32swap(x0, y0);
      pl32swap(x1, y1);
      union { unsigned wd[4]; bf16x8 v; } pk;
      pk.wd[0] = x0; pk.wd[1] = x1; pk.wd[2] = y0; pk.wd[3] = y1;
      pf[tq] = pk.v;
    }
    l_i += xsum32(rs);

    // ---- stage next tile (flies under PV) ----
    if (t + 1 < NTILES) {
      const size_t toff = (size_t)(t + 1) * TILE_ELEMS + tid * 8;
      const int nb = cur ^ 1;
      gload_lds16(KbH + toff, &Ks2[nb][tid * 8]);
      gload_lds16(KbH + toff + 2048, &Ks2[nb][2048 + tid * 8]);
      gload_lds16(VbH + toff, &Vt2[nb][tid * 8]);
      gload_lds16(VbH + toff + 2048, &Vt2[nb][2048 + tid * 8]);
    }

    // ---- O^T += V^T . P^T ----
#pragma unroll
    for (int m = 0; m < 4; ++m) {
      const int col8 = 2 * m + u;
      const int sw = (col8 ^ (ql & 7)) * 8;
      const bf16x8 va0 = *(const bf16x8*)&VtB[ql * 64 + sw];
      const bf16x8 va1 = *(const bf16x8*)&VtB[(32 + ql) * 64 + sw];
      o0 = __builtin_amdgcn_mfma_f32_32x32x16_bf16(va0, pf[m], o0, 0, 0, 0);
      o1 = __builtin_amdgcn_mfma_f32_32x32x16_bf16(va1, pf[m], o1, 0, 0, 0);
    }

    __syncthreads();  // staging done (vmcnt drained) + all reads of cur done
    cur ^= 1;
  }

  // ---- epilogue: O[q][h] = O^T / l ; h = hblk*32 + 8*rg + 4*u + r ----
  const float inv = 1.0f / l_i;
  float* orow = Og + ((size_t)(b * L_ + qr) * C_ + c) * H_;
#pragma unroll
  for (int rg = 0; rg < 4; ++rg) {
    float4 v0, v1;
    v0.x = o0[rg * 4 + 0] * inv; v0.y = o0[rg * 4 + 1] * inv;
    v0.z = o0[rg * 4 + 2] * inv; v0.w = o0[rg * 4 + 3] * inv;
    v1.x = o1[rg * 4 + 0] * inv; v1.y = o1[rg * 4 + 1] * inv;
    v1.z = o1[rg * 4 + 2] * inv; v1.w = o1[rg * 4 + 3] * inv;
    *(float4*)(orow + 8 * rg + 4 * u) = v0;
    *(float4*)(orow + 32 + 8 * rg + 4 * u) = v1;
  }
}

extern "C" void kernel_launch(void* const* d_in, const int* in_sizes, int n_in,
                              void* d_out, int out_size, void* d_ws, size_t ws_size,
                              hipStream_t stream) {
  const float* Qg = (const float*)d_in[0];
  const float* Kg = (const float*)d_in[1];
  const float* Vg = (const float*)d_in[2];
  float* Og = (float*)d_out;

  unsigned short* Kb = (unsigned short*)d_ws;
  unsigned short* Vb = Kb + (size_t)TENSOR_ELEMS;

  prepack_kernel<<<4096, 256, 0, stream>>>(Kg, Vg, Kb, Vb);

  dim3 grid(NHEADS * (L_ / QBLK));   // 512 blocks, 2 per CU
  dim3 block(NTHREADS);
  attn_fwd_kernel<<<grid, block, 0, stream>>>(Qg, Kb, Vb, Og);
}